// Round 6
// baseline (156.384 us; speedup 1.0000x reference)
//
#include <hip/hip_runtime.h>

typedef __bf16 bf16x8 __attribute__((ext_vector_type(8)));
typedef __bf16 bf16x4 __attribute__((ext_vector_type(4)));
typedef float  f32x4  __attribute__((ext_vector_type(4)));
typedef short  s16x4  __attribute__((ext_vector_type(4)));

#define B_ 4
#define T_ 2048
#define H_ 8
#define D_ 64
#define E_ 512

// q scale: D^-0.5 * log2(e)  (softmax computed in exp2 domain)
#define QSCALE 0.18033688011112042f

// async global->LDS, 16B per lane. LDS dest is wave-uniform base + lane*16.
__device__ __forceinline__ void async_ld16(const __bf16* g, __bf16* lds) {
  __builtin_amdgcn_global_load_lds((const __attribute__((address_space(1))) void*)g,
                                   (__attribute__((address_space(3))) void*)lds,
                                   16, 0, 0);
}

// 16x16x16 bf16 MFMA (K=16). A/B: 4 bf16 (2 VGPRs), lane&15 = row/col,
// k = (lane>>4)*4 + j. C/D: col=lane&15, row=(lane>>4)*4+r.
__device__ __forceinline__ f32x4 mfma16(bf16x4 a, bf16x4 b, f32x4 c) {
#if __has_builtin(__builtin_amdgcn_mfma_f32_16x16x16bf16_1k)
  union { bf16x4 h; s16x4 s; } ua, ub;
  ua.h = a; ub.h = b;
  return __builtin_amdgcn_mfma_f32_16x16x16bf16_1k(ua.s, ub.s, c, 0, 0, 0);
#else
  f32x4 d;
  asm volatile("v_mfma_f32_16x16x16_bf16 %0, %1, %2, %3"
               : "=v"(d) : "v"(a), "v"(b), "v"(c));
  return d;
#endif
}

// converts x, W_qkv (row-permuted to [which][h][d] order), W_0
__global__ void cvt_all(const float* __restrict__ x, const float* __restrict__ wq,
                        const float* __restrict__ w0, __bf16* __restrict__ xb,
                        __bf16* __restrict__ wqb, __bf16* __restrict__ w0b) {
  long i = (long)(blockIdx.x * 256 + threadIdx.x) * 8;
  const float* src; __bf16* dst; long roff, woff;
  if (i < 4194304L)      { src = x;  dst = xb;  roff = i; woff = i; }
  else if (i < 4980736L) {
    src = wq; dst = wqb; roff = i - 4194304L;
    // src row r = h*192 + d*3 + which  ->  dst row = which*512 + h*64 + d
    const int r = (int)(roff >> 9), c = (int)(roff & 511);
    const int h = r / 192, rem = r - h * 192;
    const int d = rem / 3, which = rem - d * 3;
    woff = (long)(which * 512 + h * 64 + d) * 512 + c;
  }
  else                   { src = w0; dst = w0b; roff = i - 4980736L; woff = roff; }
  float4 a = *(const float4*)(src + roff);
  float4 b = *(const float4*)(src + roff + 4);
  bf16x8 o;
  o[0] = (__bf16)a.x; o[1] = (__bf16)a.y; o[2] = (__bf16)a.z; o[3] = (__bf16)a.w;
  o[4] = (__bf16)b.x; o[5] = (__bf16)b.y; o[6] = (__bf16)b.z; o[7] = (__bf16)b.w;
  *(bf16x8*)(dst + woff) = o;
}

// C = A(MxK) * B(NxK)^T, K=512, TMx128 tile, 4 waves, 16x16x32 bf16 MFMA.
// BK=32, 3-slot LDS ring, prefetch depth 2, counted vmcnt (T3/T4).
// MODE 0 (TM=128): qkv epilogue (W pre-permuted -> which = n0>>9 block-uniform).
// MODE 1: plain fp32 store, row-major MxN.
template<int MODE, int N, int TM>
__global__ __launch_bounds__(256, TM == 128 ? 3 : 4)
void gemm_bt(const __bf16* __restrict__ A, const __bf16* __restrict__ Bm,
             __bf16* __restrict__ o0, __bf16* __restrict__ o1, __bf16* __restrict__ o2,
             float* __restrict__ of) {
  constexpr int K = 512;
  constexpr int MI = TM / 32;                 // acc tiles in m per wave
  constexpr int AL = TM / 64;                 // A slab-loads per wave per stage
  __shared__ __bf16 As[3][TM * 32];
  __shared__ __bf16 Bs[3][128 * 32];
  const int tid  = threadIdx.x;
  const int wave = tid >> 6, lane = tid & 63;
  const int l15 = lane & 15, l16 = lane >> 4;
  const int m0 = blockIdx.y * TM, n0 = blockIdx.x * 128;
  const int waveM = wave >> 1, waveN = wave & 1;
  // staging lane map: 16-row slab of 32 cols (64 B/row); lane -> (row, chunk)
  const int lr  = lane >> 2;
  const int lc8 = ((lane & 3) ^ ((lane >> 3) & 3)) * 8;

  f32x4 acc[MI][4] = {};

  const __bf16* ag = A  + (size_t)(m0 + wave * (AL * 16) + lr) * K + lc8;
  const __bf16* bg = Bm + (size_t)(n0 + wave * 32 + lr) * K + lc8;

  auto stage = [&](int buf, int k0) {
#pragma unroll
    for (int it = 0; it < AL; ++it)
      async_ld16(ag + (size_t)it * 16 * K + k0, &As[buf][(wave * AL + it) * 512]);
#pragma unroll
    for (int it = 0; it < 2; ++it)
      async_ld16(bg + (size_t)it * 16 * K + k0, &Bs[buf][(wave * 2 + it) * 512]);
  };

  stage(0, 0);
  stage(1, 32);
#pragma unroll
  for (int s = 0; s < 16; ++s) {
    if (s == 15) {
      asm volatile("s_waitcnt vmcnt(0)" ::: "memory");
    } else {
      if constexpr (AL == 2) asm volatile("s_waitcnt vmcnt(4)" ::: "memory");
      else                   asm volatile("s_waitcnt vmcnt(3)" ::: "memory");
    }
    __builtin_amdgcn_s_barrier();
    if (s < 14) stage((s + 2) % 3, (s + 2) * 32);
    const __bf16* Ac = As[s % 3];
    const __bf16* Bc = Bs[s % 3];
    bf16x8 af[MI], bfr[4];
#pragma unroll
    for (int i = 0; i < MI; ++i) {
      const int rA = waveM * (TM / 2) + i * 16 + l15;
      af[i] = *(const bf16x8*)&Ac[rA * 32 + ((l16 ^ ((rA >> 1) & 3)) * 8)];
    }
#pragma unroll
    for (int i = 0; i < 4; ++i) {
      const int rB = waveN * 64 + i * 16 + l15;
      bfr[i] = *(const bf16x8*)&Bc[rB * 32 + ((l16 ^ ((rB >> 1) & 3)) * 8)];
    }
#pragma unroll
    for (int mi = 0; mi < MI; ++mi)
#pragma unroll
      for (int ni = 0; ni < 4; ++ni)
        acc[mi][ni] = __builtin_amdgcn_mfma_f32_16x16x32_bf16(af[mi], bfr[ni], acc[mi][ni], 0, 0, 0);
  }

  if constexpr (MODE == 0) {
    const int which = n0 >> 9;          // block-uniform after W permutation
    const int b = m0 >> 11;
#pragma unroll
    for (int mi = 0; mi < MI; ++mi) {
#pragma unroll
      for (int ni = 0; ni < 4; ++ni) {
        const int n = n0 + waveN * 64 + ni * 16 + l15;
        const int d = n & 63, h = (n >> 6) & 7;
        const int t = (m0 & (T_ - 1)) + waveM * (TM / 2) + mi * 16 + l16 * 4;
        const size_t bh = (size_t)(b * H_ + h);
        if (which == 0) {
          bf16x4 pv;
#pragma unroll
          for (int r = 0; r < 4; ++r) pv[r] = (__bf16)(acc[mi][ni][r] * QSCALE);
          *(bf16x4*)&o0[(bh * D_ + d) * T_ + t] = pv;            // q [B,H,D,T]
        } else if (which == 1) {
#pragma unroll
          for (int r = 0; r < 4; ++r)
            o1[(bh * T_ + t + r) * D_ + d] = (__bf16)acc[mi][ni][r];  // k [B,H,T,D]
        } else {
          bf16x4 pv;
#pragma unroll
          for (int r = 0; r < 4; ++r) pv[r] = (__bf16)acc[mi][ni][r];
          *(bf16x4*)&o2[(bh * D_ + d) * T_ + t] = pv;            // v [B,H,D,T]
        }
      }
    }
  } else {
#pragma unroll
    for (int mi = 0; mi < MI; ++mi)
#pragma unroll
      for (int ni = 0; ni < 4; ++ni)
#pragma unroll
        for (int r = 0; r < 4; ++r) {
          const int m = m0 + waveM * (TM / 2) + mi * 16 + l16 * 4 + r;
          const int n = n0 + waveN * 64 + ni * 16 + l15;
          of[(size_t)m * N + n] = acc[mi][ni][r];
        }
  }
}

// Flash attention, max-free exp2-domain. 4-slot K/V ring, ONE BARRIER PER
// 2 TILES (R4 structure), and IN-PLACE PV: the QK^T accumulator fragment
// (col=q=l15, row=t=4*l16+r per 16x16 tile) is element-for-element the
// A-operand fragment of v_mfma_f32_16x16x16_bf16 (row=l15, k=4*l16+j).
// So P = exp2(sacc) converts straight into PV A-frags in registers —
// the P LDS round-trip (8 ds_writes + lgkm drain + 4 b128 reads + swizzle
// address math per kt, on the serial QK->softmax->PV chain) is deleted,
// with zero cross-lane movement (unlike the R3 ds_bpermute attempt).
// V B-frags (k=4*l16+j) come out of the existing [64 d][64 t] LDS layout
// as ds_read_b64. l accumulates via ones-MFMA at K=16 (same C layout).
// Waves 2x2 over (t-half 32, q-half 64).
__global__ __launch_bounds__(256, 2)
void attn_kernel(const __bf16* __restrict__ Q, const __bf16* __restrict__ Kk,
                 const __bf16* __restrict__ Vt, __bf16* __restrict__ Out) {
  __shared__ __align__(16) char smem[65536];
  // K ring[4]:  0, 8192, 16384, 24576        ([64 t][64 d] swizzled)
  // V ring[4]:  32768, 40960, 49152, 57344   ([64 d][64 t] swizzled)
  float* Osh = (float*)smem;               // overlay: [2 q2][64 d][68] f32
  float* Lsh = (float*)(smem + 34816);     // overlay: [2 q2][64 q'] f32

  const int tid = threadIdx.x, wave = tid >> 6, lane = tid & 63;
  const int l15 = lane & 15, l16 = lane >> 4;
  const int tw = wave >> 1, q2 = wave & 1;
  const int bh  = blockIdx.y;
  const int t0q = blockIdx.x * 128;
  const __bf16* qptr = Q  + (size_t)bh * D_ * T_;   // [D][T], pre-scaled
  const __bf16* kptr = Kk + (size_t)bh * T_ * D_;   // [T][D]
  const __bf16* vptr = Vt + (size_t)bh * D_ * T_;   // [D][T]

  // Q fragments (wave's 64 q-cols), from [d][t]: one-time scalar loads.
  bf16x8 qf[4][2];
#pragma unroll
  for (int ni = 0; ni < 4; ++ni)
#pragma unroll
    for (int ks = 0; ks < 2; ++ks)
#pragma unroll
      for (int j = 0; j < 8; ++j)
        qf[ni][ks][j] = qptr[(size_t)(ks * 32 + l16 * 8 + j) * T_ +
                             t0q + q2 * 64 + ni * 16 + l15];

  bf16x4 ones4;
#pragma unroll
  for (int j = 0; j < 4; ++j) ones4[j] = (__bf16)1.0f;

  f32x4 oacc[4][4] = {};   // [ni(q)][nd(d)]: col=d=l15, row=q=4*l16+r
  f32x4 lacc[4] = {};      // [ni(q)]: row=q=4*l16+r

  const int srow = lane >> 3;
  const int sch  = (lane & 7) ^ srow;

  auto stage = [&](int buf, int t0k) {
    __bf16* Kd = (__bf16*)(smem + buf * 8192);
    __bf16* Vd = (__bf16*)(smem + 32768 + buf * 8192);
#pragma unroll
    for (int i = 0; i < 2; ++i) {
      const int row = i * 32 + wave * 8;
      async_ld16(kptr + (size_t)(t0k + row + srow) * D_ + sch * 8, Kd + row * 64);
      async_ld16(vptr + (size_t)(row + srow) * T_ + t0k + sch * 8, Vd + row * 64);
    }
  };

  // prologue: first two tiles in flight
  stage(0, 0);
  stage(1, 64);
#pragma unroll 2
  for (int p = 0; p < 16; ++p) {
    __builtin_amdgcn_s_waitcnt(0);
    __syncthreads();
    if (p < 15) {
      stage((2 * p + 2) & 3, (2 * p + 2) * 64);
      stage((2 * p + 3) & 3, (2 * p + 3) * 64);
    }
#pragma unroll
    for (int kk = 0; kk < 2; ++kk) {
      const int kt = 2 * p + kk;
      const __bf16* Ksc = (const __bf16*)(smem + (kt & 3) * 8192);
      const __bf16* Vtc = (const __bf16*)(smem + 32768 + (kt & 3) * 8192);

      // S^T[t'][q'] over wave's 32 t x 64 q (log2 domain via QSCALE)
      f32x4 sacc[2][4] = {};
#pragma unroll
      for (int ks = 0; ks < 2; ++ks) {
        bf16x8 kf[2];
        const int cb = ks * 4 + l16;
#pragma unroll
        for (int mi = 0; mi < 2; ++mi) {
          const int rt = tw * 32 + mi * 16 + l15;
          kf[mi] = *(const bf16x8*)&Ksc[rt * 64 + ((cb ^ (rt & 7)) * 8)];
        }
        __builtin_amdgcn_s_setprio(1);
#pragma unroll
        for (int mi = 0; mi < 2; ++mi)
#pragma unroll
          for (int ni = 0; ni < 4; ++ni)
            sacc[mi][ni] = __builtin_amdgcn_mfma_f32_16x16x32_bf16(kf[mi], qf[ni][ks], sacc[mi][ni], 0, 0, 0);
        __builtin_amdgcn_s_setprio(0);
      }

      // V B-frags for K=16 PV: lane needs V[d = nd*16+l15][t = tslab + 4*l16 + j].
      // Stored granule g_l = g_g ^ (d & 7); t = ct*8 + (l16&1)*4 + j with
      // ct = tw*4 + mi*2 + (l16>>1)  ->  (l16>>1)*8 + (l16&1)*4 == l16*4. b64.
      bf16x4 vf[2][4];
#pragma unroll
      for (int mi = 0; mi < 2; ++mi) {
        const int ct = tw * 4 + mi * 2 + (l16 >> 1);
#pragma unroll
        for (int nd = 0; nd < 4; ++nd) {
          const int rdv = nd * 16 + l15;
          vf[mi][nd] = *(const bf16x4*)&Vtc[rdv * 64 + ((ct ^ (rdv & 7)) * 8) + (l16 & 1) * 4];
        }
      }

      // P = exp2(S) -> PV A-frags in place (pa[mi][ni][j], k = 4*l16 + j)
      bf16x4 pa[2][4];
#pragma unroll
      for (int mi = 0; mi < 2; ++mi)
#pragma unroll
        for (int ni = 0; ni < 4; ++ni)
#pragma unroll
          for (int r = 0; r < 4; ++r)
            pa[mi][ni][r] = (__bf16)__builtin_amdgcn_exp2f(sacc[mi][ni][r]);

      // O += P*V (K=16, 2 t-slabs); l += P*1
      __builtin_amdgcn_s_setprio(1);
#pragma unroll
      for (int ni = 0; ni < 4; ++ni) {
#pragma unroll
        for (int nd = 0; nd < 4; ++nd)
#pragma unroll
          for (int mi = 0; mi < 2; ++mi)
            oacc[ni][nd] = mfma16(pa[mi][ni], vf[mi][nd], oacc[ni][nd]);
#pragma unroll
        for (int mi = 0; mi < 2; ++mi)
          lacc[ni] = mfma16(pa[mi][ni], ones4, lacc[ni]);
      }
      __builtin_amdgcn_s_setprio(0);
    }
  }

  // reduce O,l across t-halves; epilogue O/l -> [B,T,H*D] bf16
  __syncthreads();
  if (tw == 1) {
    float* Ow = Osh + q2 * 4352;            // [64 d][68] f32
#pragma unroll
    for (int ni = 0; ni < 4; ++ni)
#pragma unroll
      for (int nd = 0; nd < 4; ++nd)
        *(f32x4*)&Ow[(nd * 16 + l15) * 68 + ni * 16 + l16 * 4] = oacc[ni][nd];
    if (l15 == 0)
#pragma unroll
      for (int ni = 0; ni < 4; ++ni)
        *(f32x4*)&Lsh[q2 * 64 + ni * 16 + l16 * 4] = lacc[ni];
  }
  __syncthreads();
  if (tw == 0) {
    const int b = bh >> 3, hcol = (bh & 7) * D_;
    float* Ow = Osh + q2 * 4352;
#pragma unroll
    for (int ni = 0; ni < 4; ++ni) {
      const f32x4 lv = *(const f32x4*)&Lsh[q2 * 64 + ni * 16 + l16 * 4];
      f32x4 linv;
#pragma unroll
      for (int r = 0; r < 4; ++r) linv[r] = __builtin_amdgcn_rcpf(lacc[ni][r] + lv[r]);
#pragma unroll
      for (int nd = 0; nd < 4; ++nd) {
        const f32x4 op = *(const f32x4*)&Ow[(nd * 16 + l15) * 68 + ni * 16 + l16 * 4];
#pragma unroll
        for (int r = 0; r < 4; ++r) {
          const int trow = t0q + q2 * 64 + ni * 16 + l16 * 4 + r;
          Out[((size_t)b * T_ + trow) * E_ + hcol + nd * 16 + l15] =
              (__bf16)((oacc[ni][nd][r] + op[r]) * linv[r]);
        }
      }
    }
  }
}

extern "C" void kernel_launch(void* const* d_in, const int* in_sizes, int n_in,
                              void* d_out, int out_size, void* d_ws, size_t ws_size,
                              hipStream_t stream) {
  const float* x    = (const float*)d_in[0];
  const float* Wqkv = (const float*)d_in[1];
  const float* W0   = (const float*)d_in[2];
  float* out = (float*)d_out;

  char* ws = (char*)d_ws;
  __bf16* xb  = (__bf16*)ws;                                    // 8192*512 bf16
  __bf16* wqb = (__bf16*)(ws + 8388608);                        // 1536*512 (permuted)
  __bf16* w0b = (__bf16*)(ws + 8388608 + 1572864);              // 512*512
  __bf16* q   = (__bf16*)(ws + 8388608 + 1572864 + 524288);     // [B,H,D,T]
  __bf16* k   = q + 4194304;                                    // [B,H,T,D]
  __bf16* v   = k + 4194304;                                    // [B,H,D,T]
  __bf16* ao  = xb;  // reuse: xb consumed by QKV GEMM before attn writes ao

  cvt_all<<<2560, 256, 0, stream>>>(x, Wqkv, W0, xb, wqb, w0b);
  gemm_bt<0, 3 * H_ * D_, 128><<<dim3(12, 64), 256, 0, stream>>>(xb, wqb, q, k, v, nullptr);
  attn_kernel<<<dim3(16, 32), 256, 0, stream>>>(q, k, v, ao);
  gemm_bt<1, E_, 64><<<dim3(4, 128), 256, 0, stream>>>(ao, w0b, nullptr, nullptr, nullptr, out);
}